// Round 1
// baseline (472.137 us; speedup 1.0000x reference)
//
#include <hip/hip_runtime.h>

#define BB 4096      // batch rows
#define DD 1024      // feature dim
#define RTS (BB + 16) // padded per-scale stride for rt (avoid OOB eager load)
#define BK 32        // K-step per pipeline group
#define NT (DD / BK) // 32 K-tiles

typedef float f32x4 __attribute__((ext_vector_type(4)));
typedef short bf16x8 __attribute__((ext_vector_type(8)));

__device__ __forceinline__ unsigned short f2bf(float f) {
  unsigned u = __float_as_uint(f);
  unsigned r = u + 0x7fffu + ((u >> 16) & 1u);
  return (unsigned short)(r >> 16);
}

__device__ __forceinline__ void async16(const void* g, void* l) {
  __builtin_amdgcn_global_load_lds(
      (const __attribute__((address_space(1))) void*)g,
      (__attribute__((address_space(3))) void*)l,
      16, 0, 0);
}

// ---------------- Phase 1: normalize anchor rows -> bf16 ----------------
__global__ __launch_bounds__(256) void norm_anchor(const float* __restrict__ x,
                                                   unsigned short* __restrict__ y) {
  __shared__ float sred[4];
  const int row = blockIdx.x;
  const int tid = threadIdx.x;
  const float4 v = ((const float4*)(x + (size_t)row * DD))[tid];
  float ss = v.x * v.x + v.y * v.y + v.z * v.z + v.w * v.w;
#pragma unroll
  for (int off = 32; off > 0; off >>= 1) ss += __shfl_xor(ss, off, 64);
  if ((tid & 63) == 0) sred[tid >> 6] = ss;
  __syncthreads();
  const float tot = sred[0] + sred[1] + sred[2] + sred[3];
  const float inv = 1.0f / fmaxf(sqrtf(tot), 1e-12f);
  ushort4 o;
  o.x = f2bf(v.x * inv);
  o.y = f2bf(v.y * inv);
  o.z = f2bf(v.z * inv);
  o.w = f2bf(v.w * inv);
  ((ushort4*)(y + (size_t)row * DD))[tid] = o;
}

// ------- Phase 2: gather centroid row per (j, scale), normalize -> bf16; 1/temp; zero acc -------
__global__ __launch_bounds__(256) void gather_norm(
    const int* __restrict__ index,
    const int* __restrict__ i2c0, const int* __restrict__ i2c1, const int* __restrict__ i2c2,
    const float* __restrict__ c0, const float* __restrict__ c1, const float* __restrict__ c2,
    const float* __restrict__ d0, const float* __restrict__ d1, const float* __restrict__ d2,
    unsigned short* __restrict__ p16, float* __restrict__ rt,
    float* __restrict__ rowacc) {
  __shared__ float sred[4];
  const int j = blockIdx.x;
  const int s = blockIdx.y;
  const int tid = threadIdx.x;
  const int* i2c = (s == 0) ? i2c0 : (s == 1) ? i2c1 : i2c2;
  const float* cent = (s == 0) ? c0 : (s == 1) ? c1 : c2;
  const float* dens = (s == 0) ? d0 : (s == 1) ? d1 : d2;
  const int pid = i2c[index[j]];
  const float4 v = ((const float4*)(cent + (size_t)pid * DD))[tid];
  float ss = v.x * v.x + v.y * v.y + v.z * v.z + v.w * v.w;
#pragma unroll
  for (int off = 32; off > 0; off >>= 1) ss += __shfl_xor(ss, off, 64);
  if ((tid & 63) == 0) sred[tid >> 6] = ss;
  __syncthreads();
  const float tot = sred[0] + sred[1] + sred[2] + sred[3];
  const float inv = 1.0f / fmaxf(sqrtf(tot), 1e-12f);
  unsigned short* out = p16 + ((size_t)s * BB + j) * DD;
  ushort4 o;
  o.x = f2bf(v.x * inv);
  o.y = f2bf(v.y * inv);
  o.z = f2bf(v.z * inv);
  o.w = f2bf(v.w * inv);
  ((ushort4*)out)[tid] = o;
  if (tid == 0) rt[(size_t)s * RTS + j] = 1.0f / dens[pid];
  if (tid == 1) rowacc[(size_t)s * BB + j] = 0.0f;  // zero sum-exp accumulator
}

// -------- Phase 3: 256x256-tile pipelined sim-GEMM + fused CE epilogue --------
// 8 waves (2M x 4N), BK=32, ring of 4 LDS buffers, counted vmcnt (never 0 until
// the tail), swizzled LDS (2-bit XOR within 16x32 subtiles -> 2-way/free b128
// reads), setprio around MFMA clusters. Staging for K-tile t+3 is issued during
// group t into buf (t+3)&3 = (t-1)&3, whose reads finished before this group's
// opening barrier -> race-free by construction.
__global__ __launch_bounds__(512, 2) void gemm_ce_fused(const unsigned short* __restrict__ A,
                                                        const unsigned short* __restrict__ P,
                                                        const float* __restrict__ rt,
                                                        float* __restrict__ rowacc,
                                                        float* __restrict__ diag) {
  __shared__ __align__(16) unsigned short smem[4][2][8192];  // [buf][A/B][16KB tile]
  __shared__ float rsum[256][4];
  const int tid = threadIdx.x;
  const int lane = tid & 63;
  const int wave = tid >> 6;   // 0..7
  const int wm = wave >> 2;    // 0..1  (M half: 128 rows)
  const int wn = wave & 3;     // 0..3  (N quarter: 64 cols)
  const int m0 = blockIdx.y * 256;
  const int n0 = blockIdx.x * 256;
  const int s = blockIdx.z;
  const unsigned short* Bm = P + (size_t)s * BB * DD;
  const float* rt_s = rt + (size_t)s * RTS;

  // ---- staging lane decomposition (one 16x32-bf16 subtile = 1024B per gl_lds) ----
  // LDS dest is linear (base + lane*16); the SOURCE is pre-swizzled so that a
  // ds_read at the same XOR lands on the logical element (rule 21: both sides).
  const int row_l = lane >> 2;                                       // 0..15
  const int col_e = (((lane & 3) ^ ((row_l >> 1) & 3)) << 3);        // elem offset
  const int SA = wave * 2;                                           // subtiles SA, SA+1
  const unsigned short* pA0 = A + (size_t)(m0 + SA * 16 + row_l) * DD + col_e;
  const unsigned short* pA1 = pA0 + (size_t)16 * DD;
  const unsigned short* pB0 = Bm + (size_t)(n0 + SA * 16 + row_l) * DD + col_e;
  const unsigned short* pB1 = pB0 + (size_t)16 * DD;

  // prologue: stage K-tiles 0..2 into bufs 0..2 (12 loads/wave in flight)
#pragma unroll
  for (int tt = 0; tt < 3; ++tt) {
    async16(pA0 + tt * BK, &smem[tt][0][SA * 512]);
    async16(pA1 + tt * BK, &smem[tt][0][(SA + 1) * 512]);
    async16(pB0 + tt * BK, &smem[tt][1][SA * 512]);
    async16(pB1 + tt * BK, &smem[tt][1][(SA + 1) * 512]);
  }
  const unsigned short* qA0 = pA0 + 3 * BK;
  const unsigned short* qA1 = pA1 + 3 * BK;
  const unsigned short* qB0 = pB0 + 3 * BK;
  const unsigned short* qB1 = pB1 + 3 * BK;

  // ---- fragment-read lane offsets (swizzled; 16B aligned) ----
  const int fr = lane & 15;       // row within 16-row fragment
  const int fq = lane >> 4;       // k-slot 0..3 (8 bf16 each)
  const int aoff = fr * 32 + ((fq ^ ((fr >> 1) & 3)) << 3);  // ushort units

  f32x4 acc[8][4];
#pragma unroll
  for (int mi = 0; mi < 8; ++mi)
#pragma unroll
    for (int ni = 0; ni < 4; ++ni) acc[mi][ni] = (f32x4){0.f, 0.f, 0.f, 0.f};

  for (int t = 0; t < NT; ++t) {
    const int bt = t & 3;
    const int bs = (t + 3) & 3;
    const bool stg = (t + 3 < NT);
    // Boundary: retire exactly tile t's 4 loads (tiles t+1,t+2 stay in flight).
    if (t < NT - 2)        asm volatile("s_waitcnt vmcnt(8)" ::: "memory");
    else if (t == NT - 2)  asm volatile("s_waitcnt vmcnt(4)" ::: "memory");
    else                   asm volatile("s_waitcnt vmcnt(0)" ::: "memory");
    __builtin_amdgcn_s_barrier();
    asm volatile("" ::: "memory");  // nothing crosses above the barrier

    const unsigned short* la = &smem[bt][0][0];
    const unsigned short* lb = &smem[bt][1][0];

    // ---- phase 1: stage 2, read A(lo)+B, 16 MFMA ----
    if (stg) {
      async16(qA0, &smem[bs][0][SA * 512]);
      async16(qB0, &smem[bs][1][SA * 512]);
    }
    bf16x8 af[4], bv[4];
#pragma unroll
    for (int i = 0; i < 4; ++i) af[i] = *(const bf16x8*)&la[(wm * 8 + i) * 512 + aoff];
#pragma unroll
    for (int i = 0; i < 4; ++i) bv[i] = *(const bf16x8*)&lb[(wn * 4 + i) * 512 + aoff];
    __builtin_amdgcn_s_barrier();
    __builtin_amdgcn_s_setprio(1);
#pragma unroll
    for (int mi = 0; mi < 4; ++mi)
#pragma unroll
      for (int ni = 0; ni < 4; ++ni)
        acc[mi][ni] = __builtin_amdgcn_mfma_f32_16x16x32_bf16(af[mi], bv[ni], acc[mi][ni], 0, 0, 0);
    __builtin_amdgcn_s_setprio(0);
    __builtin_amdgcn_s_barrier();

    // ---- phase 2: stage 2, read A(hi), 16 MFMA (B reused in regs) ----
    if (stg) {
      async16(qA1, &smem[bs][0][(SA + 1) * 512]);
      async16(qB1, &smem[bs][1][(SA + 1) * 512]);
      qA0 += BK; qA1 += BK; qB0 += BK; qB1 += BK;
    }
#pragma unroll
    for (int i = 0; i < 4; ++i) af[i] = *(const bf16x8*)&la[(wm * 8 + 4 + i) * 512 + aoff];
    __builtin_amdgcn_s_barrier();
    __builtin_amdgcn_s_setprio(1);
#pragma unroll
    for (int mi = 0; mi < 4; ++mi)
#pragma unroll
      for (int ni = 0; ni < 4; ++ni)
        acc[4 + mi][ni] = __builtin_amdgcn_mfma_f32_16x16x32_bf16(af[mi], bv[ni], acc[4 + mi][ni], 0, 0, 0);
    __builtin_amdgcn_s_setprio(0);
  }

  // ---- fused CE epilogue ----
  // C layout per 16x16 tile: row=(lane>>4)*4+r, col=lane&15
  const int cm = fq * 4;
  const float rt0 = rt_s[0];
  float rtc[4], rtp[4];
#pragma unroll
  for (int ni = 0; ni < 4; ++ni) {
    const int col = n0 + wn * 64 + ni * 16 + fr;
    rtc[ni] = rt_s[col];
    rtp[ni] = rt_s[col + 1];  // padded stride makes col+1 safe
  }
#pragma unroll
  for (int mi = 0; mi < 8; ++mi) {
#pragma unroll
    for (int r = 0; r < 4; ++r) {
      const int rowi = m0 + wm * 128 + mi * 16 + cm + r;
      float esum = 0.f;
#pragma unroll
      for (int ni = 0; ni < 4; ++ni) {
        const int col = n0 + wn * 64 + ni * 16 + fr;
        const float v = acc[mi][ni][r];
        // col==rowi -> rt0 (pos, concat col 0); col<rowi -> rt[col+1]; col>rowi -> rt[col]
        const float rr = (col == rowi) ? rt0 : ((col < rowi) ? rtp[ni] : rtc[ni]);
        const float l = v * rr;
        if (col == rowi) diag[(size_t)s * BB + rowi] = l;
        esum += __expf(l);
      }
#pragma unroll
      for (int off = 1; off < 16; off <<= 1) esum += __shfl_xor(esum, off, 64);
      if (fr == 0) rsum[wm * 128 + mi * 16 + cm + r][wn] = esum;
    }
  }
  __syncthreads();
  if (tid < 256) {
    const float v = rsum[tid][0] + rsum[tid][1] + rsum[tid][2] + rsum[tid][3];
    atomicAdd(&rowacc[(size_t)s * BB + m0 + tid], v);
  }
}

// ---------------- Phase 4: loss = sum_s w_s * (log(sumexp_s) - diag_s) ----------------
__global__ __launch_bounds__(256) void finish(const float* __restrict__ rowacc,
                                              const float* __restrict__ diag,
                                              float* __restrict__ out) {
  const int i = blockIdx.x * 256 + threadIdx.x;
  const float ce0 = logf(rowacc[i]) - diag[i];
  const float ce1 = logf(rowacc[BB + i]) - diag[BB + i];
  const float ce2 = logf(rowacc[2 * BB + i]) - diag[2 * BB + i];
  out[i] = ce0 * (1.0f / 27.0f) + ce1 * (1.0f / 9.0f) + ce2 * (1.0f / 3.0f);
}

extern "C" void kernel_launch(void* const* d_in, const int* in_sizes, int n_in,
                              void* d_out, int out_size, void* d_ws, size_t ws_size,
                              hipStream_t stream) {
  const float* anchor = (const float*)d_in[0];
  const int* index    = (const int*)d_in[1];
  const int* i2c0     = (const int*)d_in[2];
  const float* c0     = (const float*)d_in[3];
  const float* de0    = (const float*)d_in[4];
  const int* i2c1     = (const int*)d_in[5];
  const float* c1     = (const float*)d_in[6];
  const float* de1    = (const float*)d_in[7];
  const int* i2c2     = (const int*)d_in[8];
  const float* c2     = (const float*)d_in[9];
  const float* de2    = (const float*)d_in[10];

  char* ws = (char*)d_ws;
  const size_t A16_OFF = 0;                                      // 8 MB
  const size_t P16_OFF = A16_OFF + (size_t)BB * DD * 2;          // 24 MB (3 scales)
  const size_t RT_OFF  = P16_OFF + (size_t)3 * BB * DD * 2;      // 3*RTS floats
  const size_t ACC_OFF = RT_OFF + (size_t)3 * RTS * 4;           // 48 KB
  const size_t DIA_OFF = ACC_OFF + (size_t)3 * BB * 4;           // 48 KB

  unsigned short* a16 = (unsigned short*)(ws + A16_OFF);
  unsigned short* p16 = (unsigned short*)(ws + P16_OFF);
  float* rt     = (float*)(ws + RT_OFF);
  float* rowacc = (float*)(ws + ACC_OFF);
  float* diag   = (float*)(ws + DIA_OFF);
  float* out = (float*)d_out;

  norm_anchor<<<BB, 256, 0, stream>>>(anchor, a16);
  gather_norm<<<dim3(BB, 3), 256, 0, stream>>>(index, i2c0, i2c1, i2c2,
                                               c0, c1, c2, de0, de1, de2, p16, rt, rowacc);
  gemm_ce_fused<<<dim3(BB / 256, BB / 256, 3), 512, 0, stream>>>(a16, p16, rt, rowacc, diag);
  finish<<<BB / 256, 256, 0, stream>>>(rowacc, diag, out);
}

// Round 3
// 452.612 us; speedup vs baseline: 1.0431x; 1.0431x over previous
//
#include <hip/hip_runtime.h>

#define BB 4096      // batch rows
#define DD 1024      // feature dim
#define RTS (BB + 16) // padded per-scale stride for rt (avoid OOB eager load)
#define BK 32        // K-step per pipeline iteration
#define NT (DD / BK) // 32 K-tiles

typedef float f32x4 __attribute__((ext_vector_type(4)));
typedef short bf16x8 __attribute__((ext_vector_type(8)));

__device__ __forceinline__ unsigned short f2bf(float f) {
  unsigned u = __float_as_uint(f);
  unsigned r = u + 0x7fffu + ((u >> 16) & 1u);
  return (unsigned short)(r >> 16);
}

__device__ __forceinline__ void async16(const void* g, void* l) {
  __builtin_amdgcn_global_load_lds(
      (const __attribute__((address_space(1))) void*)g,
      (__attribute__((address_space(3))) void*)l,
      16, 0, 0);
}

// ---------------- Phase 1: normalize anchor rows -> bf16 ----------------
__global__ __launch_bounds__(256) void norm_anchor(const float* __restrict__ x,
                                                   unsigned short* __restrict__ y) {
  __shared__ float sred[4];
  const int row = blockIdx.x;
  const int tid = threadIdx.x;
  const float4 v = ((const float4*)(x + (size_t)row * DD))[tid];
  float ss = v.x * v.x + v.y * v.y + v.z * v.z + v.w * v.w;
#pragma unroll
  for (int off = 32; off > 0; off >>= 1) ss += __shfl_xor(ss, off, 64);
  if ((tid & 63) == 0) sred[tid >> 6] = ss;
  __syncthreads();
  const float tot = sred[0] + sred[1] + sred[2] + sred[3];
  const float inv = 1.0f / fmaxf(sqrtf(tot), 1e-12f);
  ushort4 o;
  o.x = f2bf(v.x * inv);
  o.y = f2bf(v.y * inv);
  o.z = f2bf(v.z * inv);
  o.w = f2bf(v.w * inv);
  ((ushort4*)(y + (size_t)row * DD))[tid] = o;
}

// ------- Phase 2: gather centroid row per (j, scale), normalize -> bf16; 1/temp; zero acc -------
__global__ __launch_bounds__(256) void gather_norm(
    const int* __restrict__ index,
    const int* __restrict__ i2c0, const int* __restrict__ i2c1, const int* __restrict__ i2c2,
    const float* __restrict__ c0, const float* __restrict__ c1, const float* __restrict__ c2,
    const float* __restrict__ d0, const float* __restrict__ d1, const float* __restrict__ d2,
    unsigned short* __restrict__ p16, float* __restrict__ rt,
    float* __restrict__ rowacc) {
  __shared__ float sred[4];
  const int j = blockIdx.x;
  const int s = blockIdx.y;
  const int tid = threadIdx.x;
  const int* i2c = (s == 0) ? i2c0 : (s == 1) ? i2c1 : i2c2;
  const float* cent = (s == 0) ? c0 : (s == 1) ? c1 : c2;
  const float* dens = (s == 0) ? d0 : (s == 1) ? d1 : d2;
  const int pid = i2c[index[j]];
  const float4 v = ((const float4*)(cent + (size_t)pid * DD))[tid];
  float ss = v.x * v.x + v.y * v.y + v.z * v.z + v.w * v.w;
#pragma unroll
  for (int off = 32; off > 0; off >>= 1) ss += __shfl_xor(ss, off, 64);
  if ((tid & 63) == 0) sred[tid >> 6] = ss;
  __syncthreads();
  const float tot = sred[0] + sred[1] + sred[2] + sred[3];
  const float inv = 1.0f / fmaxf(sqrtf(tot), 1e-12f);
  unsigned short* out = p16 + ((size_t)s * BB + j) * DD;
  ushort4 o;
  o.x = f2bf(v.x * inv);
  o.y = f2bf(v.y * inv);
  o.z = f2bf(v.z * inv);
  o.w = f2bf(v.w * inv);
  ((ushort4*)out)[tid] = o;
  if (tid == 0) rt[(size_t)s * RTS + j] = 1.0f / dens[pid];
  if (tid == 1) rowacc[(size_t)s * BB + j] = 0.0f;  // zero sum-exp accumulator
}

// -------- Phase 3: 256x256-tile sim-GEMM + fused CE epilogue --------
// 8 waves (2M x 4N), BK=32, ring of 4 LDS buffers, depth-3 prefetch with
// counted vmcnt(8) (never a drain of just-issued loads), swizzled LDS
// (2-bit XOR within 16x32 subtiles -> conflict-free b128 reads, measured 0),
// and ONE barrier + ONE s_waitcnt per K-step: staging, 12 ds_reads and
// 32 MFMAs form a single loose region the compiler fine-schedules.
// Hazards: (a) reads of buf t&3 need tile t's stores retired -> per-wave
// vmcnt(8) + barrier; (b) restaging buf (t-1)&3 needs iter t-1's ds_reads
// complete -> lgkmcnt(0) folded into the same wait (costs ~0: those reads
// were consumed by MFMAs already).
__global__ __launch_bounds__(512, 2) void gemm_ce_fused(const unsigned short* __restrict__ A,
                                                        const unsigned short* __restrict__ P,
                                                        const float* __restrict__ rt,
                                                        float* __restrict__ rowacc,
                                                        float* __restrict__ diag) {
  __shared__ __align__(16) unsigned short smem[4][2][16][512];  // [buf][A/B][subtile][elem] 128 KB
  __shared__ float rsum[256][4];
  const int tid = threadIdx.x;
  const int lane = tid & 63;
  const int wave = tid >> 6;   // 0..7
  const int wm = wave >> 2;    // 0..1  (M half: 128 rows)
  const int wn = wave & 3;     // 0..3  (N quarter: 64 cols)
  const int m0 = blockIdx.y * 256;
  const int n0 = blockIdx.x * 256;
  const int s = blockIdx.z;
  const unsigned short* Bm = P + (size_t)s * BB * DD;
  const float* rt_s = rt + (size_t)s * RTS;

  // ---- staging lane decomposition (one 16x32-bf16 subtile = 1024B per gl_lds) ----
  // LDS dest is linear (base + lane*16); the SOURCE is pre-swizzled so a
  // ds_read with the matching XOR lands on the logical element (rule 21).
  const int row_l = lane >> 2;                                       // 0..15
  const int col_e = (((lane & 3) ^ ((row_l >> 1) & 3)) << 3);        // elem offset
  const int SA = wave * 2;                                           // subtiles SA, SA+1
  const unsigned short* gA0 = A + (size_t)(m0 + SA * 16 + row_l) * DD + col_e;
  const unsigned short* gA1 = gA0 + (size_t)16 * DD;
  const unsigned short* gB0 = Bm + (size_t)(n0 + SA * 16 + row_l) * DD + col_e;
  const unsigned short* gB1 = gB0 + (size_t)16 * DD;

#define STAGE4(bb)                                   \
  do {                                               \
    async16(gA0, &smem[bb][0][SA][0]);               \
    async16(gA1, &smem[bb][0][SA + 1][0]);           \
    async16(gB0, &smem[bb][1][SA][0]);               \
    async16(gB1, &smem[bb][1][SA + 1][0]);           \
    gA0 += BK; gA1 += BK; gB0 += BK; gB1 += BK;      \
  } while (0)

  // prologue: stage K-tiles 0..2 into bufs 0..2 (12 loads/wave in flight)
  STAGE4(0);
  STAGE4(1);
  STAGE4(2);

  // ---- fragment-read lane offsets (swizzled; 16B aligned) ----
  const int fr = lane & 15;       // row within 16-row fragment
  const int fq = lane >> 4;       // k-slot 0..3 (8 bf16 each)
  const int aoff = fr * 32 + ((fq ^ ((fr >> 1) & 3)) << 3);  // ushort units

  f32x4 acc[8][4];
#pragma unroll
  for (int mi = 0; mi < 8; ++mi)
#pragma unroll
    for (int ni = 0; ni < 4; ++ni) acc[mi][ni] = (f32x4){0.f, 0.f, 0.f, 0.f};

  for (int t = 0; t < NT; ++t) {
    // Retire exactly tile t's 4 loads (tiles t+1,t+2 stay in flight) and
    // ensure last iteration's ds_reads are complete before restaging.
    if (t < NT - 2)       asm volatile("s_waitcnt vmcnt(8) lgkmcnt(0)" ::: "memory");
    else if (t == NT - 2) asm volatile("s_waitcnt vmcnt(4) lgkmcnt(0)" ::: "memory");
    else                  asm volatile("s_waitcnt vmcnt(0) lgkmcnt(0)" ::: "memory");
    __builtin_amdgcn_s_barrier();

    const int b = t & 3;
    if (t < NT - 3) STAGE4((t + 3) & 3);

    bf16x8 bv[4];
#pragma unroll
    for (int ni = 0; ni < 4; ++ni)
      bv[ni] = *(const bf16x8*)(&smem[b][1][wn * 4 + ni][0] + aoff);
#pragma unroll
    for (int mi = 0; mi < 8; ++mi) {
      const bf16x8 af = *(const bf16x8*)(&smem[b][0][wm * 8 + mi][0] + aoff);
#pragma unroll
      for (int ni = 0; ni < 4; ++ni)
        acc[mi][ni] = __builtin_amdgcn_mfma_f32_16x16x32_bf16(af, bv[ni], acc[mi][ni], 0, 0, 0);
    }
  }
#undef STAGE4

  // ---- fused CE epilogue ----
  // C layout per 16x16 tile: row=(lane>>4)*4+r, col=lane&15
  const int cm = fq * 4;
  const float rt0 = rt_s[0];
  float rtc[4], rtp[4];
#pragma unroll
  for (int ni = 0; ni < 4; ++ni) {
    const int col = n0 + wn * 64 + ni * 16 + fr;
    rtc[ni] = rt_s[col];
    rtp[ni] = rt_s[col + 1];  // padded stride makes col+1 safe
  }
#pragma unroll
  for (int mi = 0; mi < 8; ++mi) {
#pragma unroll
    for (int r = 0; r < 4; ++r) {
      const int rowi = m0 + wm * 128 + mi * 16 + cm + r;
      float esum = 0.f;
#pragma unroll
      for (int ni = 0; ni < 4; ++ni) {
        const int col = n0 + wn * 64 + ni * 16 + fr;
        const float v = acc[mi][ni][r];
        // col==rowi -> rt0 (pos, concat col 0); col<rowi -> rt[col+1]; col>rowi -> rt[col]
        const float rr = (col == rowi) ? rt0 : ((col < rowi) ? rtp[ni] : rtc[ni]);
        const float l = v * rr;
        if (col == rowi) diag[(size_t)s * BB + rowi] = l;
        esum += __expf(l);
      }
#pragma unroll
      for (int off = 1; off < 16; off <<= 1) esum += __shfl_xor(esum, off, 64);
      if (fr == 0) rsum[wm * 128 + mi * 16 + cm + r][wn] = esum;
    }
  }
  __syncthreads();
  if (tid < 256) {
    const float v = rsum[tid][0] + rsum[tid][1] + rsum[tid][2] + rsum[tid][3];
    atomicAdd(&rowacc[(size_t)s * BB + m0 + tid], v);
  }
}

// ---------------- Phase 4: loss = sum_s w_s * (log(sumexp_s) - diag_s) ----------------
__global__ __launch_bounds__(256) void finish(const float* __restrict__ rowacc,
                                              const float* __restrict__ diag,
                                              float* __restrict__ out) {
  const int i = blockIdx.x * 256 + threadIdx.x;
  const float ce0 = logf(rowacc[i]) - diag[i];
  const float ce1 = logf(rowacc[BB + i]) - diag[BB + i];
  const float ce2 = logf(rowacc[2 * BB + i]) - diag[2 * BB + i];
  out[i] = ce0 * (1.0f / 27.0f) + ce1 * (1.0f / 9.0f) + ce2 * (1.0f / 3.0f);
}

extern "C" void kernel_launch(void* const* d_in, const int* in_sizes, int n_in,
                              void* d_out, int out_size, void* d_ws, size_t ws_size,
                              hipStream_t stream) {
  const float* anchor = (const float*)d_in[0];
  const int* index    = (const int*)d_in[1];
  const int* i2c0     = (const int*)d_in[2];
  const float* c0     = (const float*)d_in[3];
  const float* de0    = (const float*)d_in[4];
  const int* i2c1     = (const int*)d_in[5];
  const float* c1     = (const float*)d_in[6];
  const float* de1    = (const float*)d_in[7];
  const int* i2c2     = (const int*)d_in[8];
  const float* c2     = (const float*)d_in[9];
  const float* de2    = (const float*)d_in[10];

  char* ws = (char*)d_ws;
  const size_t A16_OFF = 0;                                      // 8 MB
  const size_t P16_OFF = A16_OFF + (size_t)BB * DD * 2;          // 24 MB (3 scales)
  const size_t RT_OFF  = P16_OFF + (size_t)3 * BB * DD * 2;      // 3*RTS floats
  const size_t ACC_OFF = RT_OFF + (size_t)3 * RTS * 4;           // 48 KB
  const size_t DIA_OFF = ACC_OFF + (size_t)3 * BB * 4;           // 48 KB

  unsigned short* a16 = (unsigned short*)(ws + A16_OFF);
  unsigned short* p16 = (unsigned short*)(ws + P16_OFF);
  float* rt     = (float*)(ws + RT_OFF);
  float* rowacc = (float*)(ws + ACC_OFF);
  float* diag   = (float*)(ws + DIA_OFF);
  float* out = (float*)d_out;

  norm_anchor<<<BB, 256, 0, stream>>>(anchor, a16);
  gather_norm<<<dim3(BB, 3), 256, 0, stream>>>(index, i2c0, i2c1, i2c2,
                                               c0, c1, c2, de0, de1, de2, p16, rt, rowacc);
  gemm_ce_fused<<<dim3(BB / 256, BB / 256, 3), 512, 0, stream>>>(a16, p16, rt, rowacc, diag);
  finish<<<BB / 256, 256, 0, stream>>>(rowacc, diag, out);
}

// Round 4
// 444.311 us; speedup vs baseline: 1.0626x; 1.0187x over previous
//
#include <hip/hip_runtime.h>

#define BB 4096      // batch rows
#define DD 1024      // feature dim
#define RTS (BB + 16) // padded per-scale stride for rt (avoid OOB eager load)
#define BK 32        // K-step per pipeline iteration
#define NT (DD / BK) // 32 K-tiles

typedef float f32x4 __attribute__((ext_vector_type(4)));
typedef short bf16x8 __attribute__((ext_vector_type(8)));

__device__ __forceinline__ unsigned short f2bf(float f) {
  unsigned u = __float_as_uint(f);
  unsigned r = u + 0x7fffu + ((u >> 16) & 1u);
  return (unsigned short)(r >> 16);
}

__device__ __forceinline__ void async16(const void* g, void* l) {
  __builtin_amdgcn_global_load_lds(
      (const __attribute__((address_space(1))) void*)g,
      (__attribute__((address_space(3))) void*)l,
      16, 0, 0);
}

// ---------------- Phase 1: normalize anchor rows -> bf16 ----------------
__global__ __launch_bounds__(256) void norm_anchor(const float* __restrict__ x,
                                                   unsigned short* __restrict__ y) {
  __shared__ float sred[4];
  const int row = blockIdx.x;
  const int tid = threadIdx.x;
  const float4 v = ((const float4*)(x + (size_t)row * DD))[tid];
  float ss = v.x * v.x + v.y * v.y + v.z * v.z + v.w * v.w;
#pragma unroll
  for (int off = 32; off > 0; off >>= 1) ss += __shfl_xor(ss, off, 64);
  if ((tid & 63) == 0) sred[tid >> 6] = ss;
  __syncthreads();
  const float tot = sred[0] + sred[1] + sred[2] + sred[3];
  const float inv = 1.0f / fmaxf(sqrtf(tot), 1e-12f);
  ushort4 o;
  o.x = f2bf(v.x * inv);
  o.y = f2bf(v.y * inv);
  o.z = f2bf(v.z * inv);
  o.w = f2bf(v.w * inv);
  ((ushort4*)(y + (size_t)row * DD))[tid] = o;
}

// ------- Phase 2: gather centroid row per (j, scale), normalize -> bf16; 1/temp; zero acc -------
__global__ __launch_bounds__(256) void gather_norm(
    const int* __restrict__ index,
    const int* __restrict__ i2c0, const int* __restrict__ i2c1, const int* __restrict__ i2c2,
    const float* __restrict__ c0, const float* __restrict__ c1, const float* __restrict__ c2,
    const float* __restrict__ d0, const float* __restrict__ d1, const float* __restrict__ d2,
    unsigned short* __restrict__ p16, float* __restrict__ rt,
    float* __restrict__ rowacc) {
  __shared__ float sred[4];
  const int j = blockIdx.x;
  const int s = blockIdx.y;
  const int tid = threadIdx.x;
  const int* i2c = (s == 0) ? i2c0 : (s == 1) ? i2c1 : i2c2;
  const float* cent = (s == 0) ? c0 : (s == 1) ? c1 : c2;
  const float* dens = (s == 0) ? d0 : (s == 1) ? d1 : d2;
  const int pid = i2c[index[j]];
  const float4 v = ((const float4*)(cent + (size_t)pid * DD))[tid];
  float ss = v.x * v.x + v.y * v.y + v.z * v.z + v.w * v.w;
#pragma unroll
  for (int off = 32; off > 0; off >>= 1) ss += __shfl_xor(ss, off, 64);
  if ((tid & 63) == 0) sred[tid >> 6] = ss;
  __syncthreads();
  const float tot = sred[0] + sred[1] + sred[2] + sred[3];
  const float inv = 1.0f / fmaxf(sqrtf(tot), 1e-12f);
  unsigned short* out = p16 + ((size_t)s * BB + j) * DD;
  ushort4 o;
  o.x = f2bf(v.x * inv);
  o.y = f2bf(v.y * inv);
  o.z = f2bf(v.z * inv);
  o.w = f2bf(v.w * inv);
  ((ushort4*)out)[tid] = o;
  if (tid == 0) rt[(size_t)s * RTS + j] = 1.0f / dens[pid];
  if (tid == 1) rowacc[(size_t)s * BB + j] = 0.0f;  // zero sum-exp accumulator
}

// -------- Phase 3: 128x128-tile sim-GEMM + fused CE epilogue --------
// r0's proven shape (128^2, 4 waves, multi-block/CU for inter-block overlap)
// + r3's proven sync scheme: ring-3 LDS bufs, depth-2 prefetch, counted
// vmcnt(4) (never drains in-flight prefetch -> removes r0's __syncthreads
// vmcnt(0) stall), raw barrier, and the 0-conflict XOR swizzle.
// Hazards: iter t reads buf t%3 (own tile-t loads retired by vmcnt(4)
// pre-barrier; all waves' by the barrier). Iter t stages tile t+2 into
// buf (t+2)%3 == (t-1)%3, whose ds_reads completed before this barrier
// (their results fed iter t-1's MFMAs). 48KB LDS + launch_bounds(256,3)
// -> 3 blocks/CU.
__global__ __launch_bounds__(256, 3) void gemm_ce_fused(const unsigned short* __restrict__ A,
                                                        const unsigned short* __restrict__ P,
                                                        const float* __restrict__ rt,
                                                        float* __restrict__ rowacc,
                                                        float* __restrict__ diag) {
  __shared__ __align__(16) unsigned short lA[3][8][512];  // [buf][subtile 16x32][elem]
  __shared__ __align__(16) unsigned short lB[3][8][512];
  __shared__ float rowsum[2][128];
  const int tid = threadIdx.x;
  const int lane = tid & 63;
  const int wave = tid >> 6;   // 0..3
  const int m0 = blockIdx.y * 128;
  const int n0 = blockIdx.x * 128;
  const int s = blockIdx.z;
  const unsigned short* Bm = P + (size_t)s * BB * DD;
  const float* rt_s = rt + (size_t)s * RTS;

  // ---- staging lane decomposition (one 16x32-bf16 subtile = 1024B per gl_lds) ----
  // LDS dest linear (base + lane*16); SOURCE pre-swizzled so the matching
  // XOR on ds_read lands on the logical element (both-sides rule).
  const int row_l = lane >> 2;                                       // 0..15
  const int col_e = (((lane & 3) ^ ((row_l >> 1) & 3)) << 3);        // elem offset
  const int SA = wave * 2;                                           // subtiles SA, SA+1
  const unsigned short* gA0 = A + (size_t)(m0 + SA * 16 + row_l) * DD + col_e;
  const unsigned short* gA1 = gA0 + (size_t)16 * DD;
  const unsigned short* gB0 = Bm + (size_t)(n0 + SA * 16 + row_l) * DD + col_e;
  const unsigned short* gB1 = gB0 + (size_t)16 * DD;

#define STAGE4(bb)                               \
  do {                                           \
    async16(gA0, &lA[bb][SA][0]);                \
    async16(gA1, &lA[bb][SA + 1][0]);            \
    async16(gB0, &lB[bb][SA][0]);                \
    async16(gB1, &lB[bb][SA + 1][0]);            \
    gA0 += BK; gA1 += BK; gB0 += BK; gB1 += BK;  \
  } while (0)

  // prologue: stage K-tiles 0,1 into bufs 0,1 (8 loads/wave in flight)
  STAGE4(0);
  STAGE4(1);

  // ---- fragment-read lane offsets (swizzled; 16B aligned; measured 0-conflict) ----
  const int fr = lane & 15;       // row within 16-row fragment
  const int fq = lane >> 4;       // k-slot 0..3 (8 bf16 each)
  const int aoff = fr * 32 + ((fq ^ ((fr >> 1) & 3)) << 3);  // ushort units
  const int wm = wave >> 1;       // 0..1 (M half)
  const int wn = wave & 1;        // 0..1 (N half)

  f32x4 acc[4][4];
#pragma unroll
  for (int mi = 0; mi < 4; ++mi)
#pragma unroll
    for (int ni = 0; ni < 4; ++ni) acc[mi][ni] = (f32x4){0.f, 0.f, 0.f, 0.f};

  int bt = 0;        // buf holding tile t
  int bs = 2;        // buf to stage tile t+2 into
  for (int t = 0; t < NT; ++t) {
    // Retire exactly tile t's 4 loads (tile t+1's stay in flight).
    if (t < NT - 1) asm volatile("s_waitcnt vmcnt(4)" ::: "memory");
    else            asm volatile("s_waitcnt vmcnt(0)" ::: "memory");
    __builtin_amdgcn_s_barrier();

    if (t < NT - 2) STAGE4(bs);

    bf16x8 bv[4];
#pragma unroll
    for (int ni = 0; ni < 4; ++ni)
      bv[ni] = *(const bf16x8*)(&lB[bt][wn * 4 + ni][0] + aoff);
#pragma unroll
    for (int mi = 0; mi < 4; ++mi) {
      const bf16x8 af = *(const bf16x8*)(&lA[bt][wm * 4 + mi][0] + aoff);
#pragma unroll
      for (int ni = 0; ni < 4; ++ni)
        acc[mi][ni] = __builtin_amdgcn_mfma_f32_16x16x32_bf16(af, bv[ni], acc[mi][ni], 0, 0, 0);
    }
    bt = (bt == 2) ? 0 : bt + 1;
    bs = (bs == 2) ? 0 : bs + 1;
  }
#undef STAGE4

  // ---- fused CE epilogue (r0's proven code; wm/wn as *64 offsets) ----
  // C layout per 16x16 tile: row=(lane>>4)*4+r, col=lane&15
  const int WMO = wm * 64;
  const int WNO = wn * 64;
  const int cm = fq * 4;
  const float rt0 = rt_s[0];
  float rtc[4], rtp[4];
#pragma unroll
  for (int ni = 0; ni < 4; ++ni) {
    const int col = n0 + WNO + ni * 16 + fr;
    rtc[ni] = rt_s[col];
    rtp[ni] = rt_s[col + 1];   // padded stride makes col+1 safe
  }
#pragma unroll
  for (int mi = 0; mi < 4; ++mi) {
#pragma unroll
    for (int r = 0; r < 4; ++r) {
      const int rowi = m0 + WMO + mi * 16 + cm + r;
      float esum = 0.f;
#pragma unroll
      for (int ni = 0; ni < 4; ++ni) {
        const int col = n0 + WNO + ni * 16 + fr;
        const float v = acc[mi][ni][r];
        // col==rowi -> rt0 (pos, concat col 0); col<rowi -> rt[col+1]; col>rowi -> rt[col]
        const float rr = (col == rowi) ? rt0 : ((col < rowi) ? rtp[ni] : rtc[ni]);
        const float l = v * rr;
        if (col == rowi) diag[(size_t)s * BB + rowi] = l;
        esum += __expf(l);
      }
      // reduce across the 16 lanes of the quad (these hold the 16 cols)
#pragma unroll
      for (int off = 1; off < 16; off <<= 1) esum += __shfl_xor(esum, off, 64);
      if (fr == 0) rowsum[wn][WMO + mi * 16 + cm + r] = esum;
    }
  }
  __syncthreads();
  if (tid < 128)
    atomicAdd(&rowacc[(size_t)s * BB + m0 + tid], rowsum[0][tid] + rowsum[1][tid]);
}

// ---------------- Phase 4: loss = sum_s w_s * (log(sumexp_s) - diag_s) ----------------
__global__ __launch_bounds__(256) void finish(const float* __restrict__ rowacc,
                                              const float* __restrict__ diag,
                                              float* __restrict__ out) {
  const int i = blockIdx.x * 256 + threadIdx.x;
  const float ce0 = logf(rowacc[i]) - diag[i];
  const float ce1 = logf(rowacc[BB + i]) - diag[BB + i];
  const float ce2 = logf(rowacc[2 * BB + i]) - diag[2 * BB + i];
  out[i] = ce0 * (1.0f / 27.0f) + ce1 * (1.0f / 9.0f) + ce2 * (1.0f / 3.0f);
}

extern "C" void kernel_launch(void* const* d_in, const int* in_sizes, int n_in,
                              void* d_out, int out_size, void* d_ws, size_t ws_size,
                              hipStream_t stream) {
  const float* anchor = (const float*)d_in[0];
  const int* index    = (const int*)d_in[1];
  const int* i2c0     = (const int*)d_in[2];
  const float* c0     = (const float*)d_in[3];
  const float* de0    = (const float*)d_in[4];
  const int* i2c1     = (const int*)d_in[5];
  const float* c1     = (const float*)d_in[6];
  const float* de1    = (const float*)d_in[7];
  const int* i2c2     = (const int*)d_in[8];
  const float* c2     = (const float*)d_in[9];
  const float* de2    = (const float*)d_in[10];

  char* ws = (char*)d_ws;
  const size_t A16_OFF = 0;                                      // 8 MB
  const size_t P16_OFF = A16_OFF + (size_t)BB * DD * 2;          // 24 MB (3 scales)
  const size_t RT_OFF  = P16_OFF + (size_t)3 * BB * DD * 2;      // 3*RTS floats
  const size_t ACC_OFF = RT_OFF + (size_t)3 * RTS * 4;           // 48 KB
  const size_t DIA_OFF = ACC_OFF + (size_t)3 * BB * 4;           // 48 KB

  unsigned short* a16 = (unsigned short*)(ws + A16_OFF);
  unsigned short* p16 = (unsigned short*)(ws + P16_OFF);
  float* rt     = (float*)(ws + RT_OFF);
  float* rowacc = (float*)(ws + ACC_OFF);
  float* diag   = (float*)(ws + DIA_OFF);
  float* out = (float*)d_out;

  norm_anchor<<<BB, 256, 0, stream>>>(anchor, a16);
  gather_norm<<<dim3(BB, 3), 256, 0, stream>>>(index, i2c0, i2c1, i2c2,
                                               c0, c1, c2, de0, de1, de2, p16, rt, rowacc);
  gemm_ce_fused<<<dim3(BB / 128, BB / 128, 3), 256, 0, stream>>>(a16, p16, rt, rowacc, diag);
  finish<<<BB / 256, 256, 0, stream>>>(rowacc, diag, out);
}